// Round 8
// baseline (5753.786 us; speedup 1.0000x reference)
//
#include <hip/hip_runtime.h>
#include <cstddef>

#define B_SZ 32
#define T_LEN 1000
#define LN_EPS 1e-5f

typedef short bf16x8 __attribute__((ext_vector_type(8)));
typedef float f32x4 __attribute__((ext_vector_type(4)));

__device__ __forceinline__ unsigned short f2bf(float f) {
    unsigned u = __builtin_bit_cast(unsigned, f);
    u += 0x7FFFu + ((u >> 16) & 1u);          // RNE
    return (unsigned short)(u >> 16);
}

// ---------------------------------------------------------------------------
// kw: pack w_rec [1024][512] f32 into bf16 B-fragments for mfma 16x16x32.
// ---------------------------------------------------------------------------
__global__ __launch_bounds__(256) void kw(const float* __restrict__ w_rec,
                                          unsigned short* __restrict__ wrt) {
    int idx  = blockIdx.x * 256 + threadIdx.x;   // 65536 total
    int lane = idx & 63;
    int nt   = (idx >> 6) & 63;
    int kt   = idx >> 12;
    int n    = nt * 16 + (lane & 15);
    int k0   = kt * 32 + (lane >> 4) * 8;
    const float* src = w_rec + (size_t)n * 512 + k0;
    unsigned short* dst = wrt + (size_t)idx * 8;
#pragma unroll
    for (int j = 0; j < 8; ++j) dst[j] = f2bf(src[j]);
}

// ---------------------------------------------------------------------------
// k1: grouped input projection x @ w_in -> h_in (bf16). 16 rows/block.
// ---------------------------------------------------------------------------
__global__ __launch_bounds__(256) void k1(const float* __restrict__ x,
                                          const float* __restrict__ w_in,   // [g][i][o]
                                          unsigned short* __restrict__ hin) {
    __shared__ alignas(16) float xt[16][512];
    const int tid  = threadIdx.x;
    const int row0 = blockIdx.x * 16;

    for (int i = tid; i < 16 * 128; i += 256) {
        int rr = i >> 7, c4 = i & 127;
        ((float4*)xt[rr])[c4] =
            ((const float4*)(x + (size_t)(row0 + rr) * 512))[c4];
    }
    __syncthreads();

    for (int q = 0; q < 2; ++q) {
        const int c = tid + (q << 8);
        const int g = c >> 6, o = c & 63;
        const float* wb = w_in + (g << 12) + o;
        float wcol[64];
#pragma unroll
        for (int ii = 0; ii < 64; ++ii) wcol[ii] = wb[ii << 6];
#pragma unroll 4
        for (int rr = 0; rr < 16; ++rr) {
            float acc = 0.f;
#pragma unroll
            for (int ii = 0; ii < 64; ++ii) acc += xt[rr][(g << 6) + ii] * wcol[ii];
            hin[(size_t)(row0 + rr) * 512 + c] = f2bf(acc);
        }
    }
}

// ---------------------------------------------------------------------------
// k2: w_pre = LayerNorm(h_in @ w_rec^T) via MFMA 16x16x32 bf16 (as R7).
// ---------------------------------------------------------------------------
#define ALD 536
__global__ __launch_bounds__(256) void k2(const unsigned short* __restrict__ hin,
                                          const unsigned short* __restrict__ wrt,
                                          const float* __restrict__ gamma,
                                          const float* __restrict__ beta,
                                          float* __restrict__ w_pre) {
    __shared__ alignas(16) unsigned short At[32 * ALD];
    __shared__ float redS[4][32];
    __shared__ float redQ[4][32];
    __shared__ float stat[2][32];

    const int tid  = threadIdx.x;
    const int w    = tid >> 6;
    const int l    = tid & 63;
    const int kgrp = l >> 4;
    const int lc   = l & 15;
    const int row0 = blockIdx.x * 32;

    for (int sidx = tid; sidx < 2048; sidx += 256) {
        int r = sidx >> 6, sg = sidx & 63;
        *(bf16x8*)(At + r * ALD + sg * 8) =
            *(const bf16x8*)(hin + (size_t)(row0 + r) * 512 + sg * 8);
    }
    __syncthreads();

    f32x4 acc[2][16];
#pragma unroll
    for (int fr = 0; fr < 2; ++fr)
#pragma unroll
        for (int n = 0; n < 16; ++n) acc[fr][n] = f32x4{0.f, 0.f, 0.f, 0.f};

    for (int kt = 0; kt < 16; ++kt) {
        bf16x8 a0 = *(const bf16x8*)(At + (lc)      * ALD + kt * 32 + kgrp * 8);
        bf16x8 a1 = *(const bf16x8*)(At + (16 + lc) * ALD + kt * 32 + kgrp * 8);
        const unsigned short* bb =
            wrt + (((size_t)kt * 64 + w * 16) * 64 + l) * 8;
#pragma unroll
        for (int ntl = 0; ntl < 16; ++ntl) {
            bf16x8 bf = *(const bf16x8*)(bb + (size_t)ntl * 512);
            acc[0][ntl] = __builtin_amdgcn_mfma_f32_16x16x32_bf16(a0, bf, acc[0][ntl], 0, 0, 0);
            acc[1][ntl] = __builtin_amdgcn_mfma_f32_16x16x32_bf16(a1, bf, acc[1][ntl], 0, 0, 0);
        }
    }

    float sums[2][4] = {{0.f}}, sqs[2][4] = {{0.f}};
#pragma unroll
    for (int fr = 0; fr < 2; ++fr)
#pragma unroll
        for (int ntl = 0; ntl < 16; ++ntl)
#pragma unroll
            for (int r = 0; r < 4; ++r) {
                float v = acc[fr][ntl][r];
                sums[fr][r] += v;
                sqs[fr][r]  += v * v;
            }
#pragma unroll
    for (int off = 1; off < 16; off <<= 1)
#pragma unroll
        for (int fr = 0; fr < 2; ++fr)
#pragma unroll
            for (int r = 0; r < 4; ++r) {
                sums[fr][r] += __shfl_xor(sums[fr][r], off);
                sqs[fr][r]  += __shfl_xor(sqs[fr][r], off);
            }
    if (lc == 0) {
#pragma unroll
        for (int fr = 0; fr < 2; ++fr)
#pragma unroll
            for (int r = 0; r < 4; ++r) {
                redS[w][fr * 16 + kgrp * 4 + r] = sums[fr][r];
                redQ[w][fr * 16 + kgrp * 4 + r] = sqs[fr][r];
            }
    }
    __syncthreads();
    if (tid < 32) {
        float S = redS[0][tid] + redS[1][tid] + redS[2][tid] + redS[3][tid];
        float Q = redQ[0][tid] + redQ[1][tid] + redQ[2][tid] + redQ[3][tid];
        float mu  = S * (1.f / 1024.f);
        float var = Q * (1.f / 1024.f) - mu * mu;
        stat[0][tid] = mu;
        stat[1][tid] = rsqrtf(var + LN_EPS);
    }
    __syncthreads();

#pragma unroll
    for (int ntl = 0; ntl < 16; ++ntl) {
        const int col = (w << 8) + (ntl << 4) + lc;
        const float g = gamma[col], bt = beta[col];
#pragma unroll
        for (int fr = 0; fr < 2; ++fr)
#pragma unroll
            for (int r = 0; r < 4; ++r) {
                const int row = fr * 16 + kgrp * 4 + r;
                const float mu  = stat[0][row];
                const float inv = stat[1][row];
                w_pre[((size_t)(row0 + row) << 10) + col] =
                    (acc[fr][ntl][r] - mu) * inv * g + bt;
            }
    }
}

// ---------------------------------------------------------------------------
// LiGRU scan, 8 blocks/batch, dataflow-stamp sync, SINGLE barrier per step.
// Row interleave: row 2j = a-gate of h[j], row 2j+1 = z-gate of h[j].
// After kk-reduce (shfl_xor 1,2,4), shfl_xor 8 exchanges the paired gate ->
// every lane of a j-group computes the identical h-update in registers
// (hreg replicated x16). No gsum LDS, no second syncthreads.
// hsh double-buffered (single-barrier safety: a wave at poll(t+2) implies all
// waves passed barrier(t+1), hence finished dot(t) reads of buffer t&1).
// Polls are 8B (both words stamped); producer stores 4 stamped words + one
// exact float4 of h history per wave.
// ---------------------------------------------------------------------------
__global__ __launch_bounds__(1024) void k_scan(const float* __restrict__ w_pre,
                                               const float* __restrict__ u,   // [1024][512]
                                               float* __restrict__ hs,        // [B][T][512]
                                               unsigned int* hbuf) {          // [2][32][512]
    __shared__ alignas(16) float hsh[2][512];

    const int tid = threadIdx.x;
    const int b   = blockIdx.x & 31;
    const int s   = blockIdx.x >> 5;
    const int J0  = s << 6;
    const int row = tid >> 3;        // 0..127
    const int kk  = tid & 7;
    const int jh  = row >> 1;        // local j: 0..63
    const int jj  = (row & 1) ? (512 + J0 + jh) : (J0 + jh);

    // ---- u slice -> registers (one-time, f32) ----
    float ur[64];
    {
        const float4* up = (const float4*)(u + (size_t)jj * 512 + (kk << 6));
#pragma unroll
        for (int m = 0; m < 16; ++m) {
            float4 v = up[m];
            ur[4 * m + 0] = v.x; ur[4 * m + 1] = v.y;
            ur[4 * m + 2] = v.z; ur[4 * m + 3] = v.w;
        }
    }

    const float* wbase = w_pre + ((size_t)b * T_LEN) * 1024 + jj;
    const int wv = tid >> 6;         // wave 0..15; wave covers j = 4wv..4wv+3
    const int ln = tid & 63;
    float* outrow = hs + ((size_t)b * T_LEN) * 512 + J0 + (wv << 2);

    float hreg = 0.f;                // replicated h[jh] across the 16-lane j-group

    for (int t = 0; t < T_LEN; ++t) {
        unsigned int* in_w  = hbuf + ((((t & 1) << 5) | b) << 9);
        unsigned int* out_w = hbuf + (((((t + 1) & 1) << 5) | b) << 9);

        // prefetch this step's w (overlaps the poll)
        float wreg = 0.f;
        if (kk == 0) wreg = wbase[(size_t)t << 10];

        // ---- poll (8B, both words stamped) + stage to swizzled LDS ----
        if (tid < 256) {
            const unsigned long long* src = (const unsigned long long*)in_w + tid;
            const unsigned int want = (unsigned)t & 3u;
            unsigned long long v = __hip_atomic_load(src, __ATOMIC_RELAXED,
                                                     __HIP_MEMORY_SCOPE_AGENT);
            while (((unsigned)v & 3u) != want ||
                   ((unsigned)(v >> 32) & 3u) != want) {
                v = __hip_atomic_load(src, __ATOMIC_RELAXED,
                                      __HIP_MEMORY_SCOPE_AGENT);
            }
            int c = tid >> 1, half = tid & 1;
            int a = (c & ~7) | ((c ^ (c >> 4)) & 7);
            *(unsigned long long*)((char*)hsh[t & 1] + (a << 4) + (half << 3)) = v;
        }
        __syncthreads();   // the ONLY barrier per step

        // ---- dot: 64 MACs via 16 conflict-free float4 LDS reads ----
        const char* hb8 = (const char*)hsh[t & 1];
        float a0 = 0.f, a1 = 0.f, a2 = 0.f, a3 = 0.f;
        const int base = kk << 8;
#pragma unroll
        for (int i = 0; i < 16; ++i) {
            int off = base + (((i & 8) | ((i ^ kk) & 7)) << 4);
            float4 hv = *(const float4*)(hb8 + off);
            a0 += ur[4 * i + 0] * hv.x;
            a1 += ur[4 * i + 1] * hv.y;
            a2 += ur[4 * i + 2] * hv.z;
            a3 += ur[4 * i + 3] * hv.w;
        }
        float acc = (a0 + a1) + (a2 + a3) + wreg;   // wreg only on kk==0
        acc += __shfl_xor(acc, 1);
        acc += __shfl_xor(acc, 2);
        acc += __shfl_xor(acc, 4);                  // all 8 lanes: gate(row)
        float other = __shfl_xor(acc, 8);           // gate(row^1)
        float ga = (row & 1) ? other : acc;
        float gz = (row & 1) ? acc : other;
        float z  = 1.f / (1.f + __expf(-gz));
        float hn = z * hreg + (1.f - z) * fmaxf(ga, 0.f);
        hreg = hn;

        // ---- producer: lane 0 of each wave stores its wave's 4 h values ----
        float h1 = __shfl(hn, 16, 64);
        float h2 = __shfl(hn, 32, 64);
        float h3 = __shfl(hn, 48, 64);
        if (ln == 0) {
            const unsigned int stamp = (unsigned)(t + 1) & 3u;
            unsigned int b0 = (__builtin_bit_cast(unsigned int, hn) & ~3u) | stamp;
            unsigned int b1 = (__builtin_bit_cast(unsigned int, h1) & ~3u) | stamp;
            unsigned int b2 = (__builtin_bit_cast(unsigned int, h2) & ~3u) | stamp;
            unsigned int b3 = (__builtin_bit_cast(unsigned int, h3) & ~3u) | stamp;
            unsigned int* dst = out_w + J0 + (wv << 2);
            __hip_atomic_store(dst + 0, b0, __ATOMIC_RELAXED, __HIP_MEMORY_SCOPE_AGENT);
            __hip_atomic_store(dst + 1, b1, __ATOMIC_RELAXED, __HIP_MEMORY_SCOPE_AGENT);
            __hip_atomic_store(dst + 2, b2, __ATOMIC_RELAXED, __HIP_MEMORY_SCOPE_AGENT);
            __hip_atomic_store(dst + 3, b3, __ATOMIC_RELAXED, __HIP_MEMORY_SCOPE_AGENT);
            *(float4*)(outrow + ((size_t)t << 9)) = float4{hn, h1, h2, h3};
        }
    }
}

// ---------------------------------------------------------------------------
// Output grouped linear, in-place on d_out (holds hs after k_scan).
// ---------------------------------------------------------------------------
__global__ __launch_bounds__(256) void k_out(const float* __restrict__ w_out, // [g][i][o]
                                             float* __restrict__ io) {
    __shared__ alignas(16) float ht[8][512];
    const int tid  = threadIdx.x;
    const int row0 = blockIdx.x * 8;

    for (int i = tid; i < 8 * 128; i += 256) {
        int rr = i >> 7, c4 = i & 127;
        ((float4*)ht[rr])[c4] =
            ((const float4*)(io + (size_t)(row0 + rr) * 512))[c4];
    }
    __syncthreads();

    for (int q = 0; q < 2; ++q) {
        const int c = tid + (q << 8);
        const int g = c >> 6, o = c & 63;
        const float* wb = w_out + (g << 12) + o;
        float wcol[64];
#pragma unroll
        for (int ii = 0; ii < 64; ++ii) wcol[ii] = wb[ii << 6];
#pragma unroll 4
        for (int rr = 0; rr < 8; ++rr) {
            float acc = 0.f;
#pragma unroll
            for (int ii = 0; ii < 64; ++ii) acc += ht[rr][(g << 6) + ii] * wcol[ii];
            io[(size_t)(row0 + rr) * 512 + c] = acc;
        }
    }
}

// ---------------------------------------------------------------------------
extern "C" void kernel_launch(void* const* d_in, const int* in_sizes, int n_in,
                              void* d_out, int out_size, void* d_ws, size_t ws_size,
                              hipStream_t stream) {
    const float* x      = (const float*)d_in[0];
    const float* w_in   = (const float*)d_in[1];
    const float* w_rec  = (const float*)d_in[2];
    const float* u_rec  = (const float*)d_in[3];
    const float* gamma  = (const float*)d_in[4];
    const float* beta   = (const float*)d_in[5];
    const float* w_out  = (const float*)d_in[6];
    float* out = (float*)d_out;

    // workspace layout (131,203,072 B — proven bound)
    float*        w_pre = (float*)d_ws;                       // 32,768,000 f32
    unsigned int* hbuf  = (unsigned int*)(w_pre + (size_t)32 * T_LEN * 1024); // [2][32][512]

    // d_out staging (dead until k_scan overwrites it)
    unsigned short* hin = (unsigned short*)d_out;
    unsigned short* wrt = hin + (size_t)32000 * 512;

    hipLaunchKernelGGL(kw, dim3(256), dim3(256), 0, stream, w_rec, wrt);
    hipLaunchKernelGGL(k1, dim3(2000), dim3(256), 0, stream, x, w_in, hin);
    hipLaunchKernelGGL(k2, dim3(1000), dim3(256), 0, stream,
                       hin, wrt, gamma, beta, w_pre);
    hipMemsetAsync(hbuf, 0, 2 * 32 * 512 * sizeof(unsigned int), stream);
    hipLaunchKernelGGL(k_scan, dim3(256), dim3(1024), 0, stream,
                       w_pre, u_rec, out, hbuf);
    hipLaunchKernelGGL(k_out, dim3(4000), dim3(256), 0, stream, w_out, out);
}

// Round 9
// 1906.501 us; speedup vs baseline: 3.0180x; 3.0180x over previous
//
#include <hip/hip_runtime.h>
#include <cstddef>

#define B_SZ 32
#define T_LEN 1000
#define LN_EPS 1e-5f

typedef short bf16x8 __attribute__((ext_vector_type(8)));
typedef float f32x4 __attribute__((ext_vector_type(4)));

__device__ __forceinline__ unsigned short f2bf(float f) {
    unsigned u = __builtin_bit_cast(unsigned, f);
    u += 0x7FFFu + ((u >> 16) & 1u);          // RNE
    return (unsigned short)(u >> 16);
}

// ---------------------------------------------------------------------------
// kw: pack w_rec [1024][512] f32 into bf16 B-fragments for mfma 16x16x32.
// ---------------------------------------------------------------------------
__global__ __launch_bounds__(256) void kw(const float* __restrict__ w_rec,
                                          unsigned short* __restrict__ wrt) {
    int idx  = blockIdx.x * 256 + threadIdx.x;   // 65536 total
    int lane = idx & 63;
    int nt   = (idx >> 6) & 63;
    int kt   = idx >> 12;
    int n    = nt * 16 + (lane & 15);
    int k0   = kt * 32 + (lane >> 4) * 8;
    const float* src = w_rec + (size_t)n * 512 + k0;
    unsigned short* dst = wrt + (size_t)idx * 8;
#pragma unroll
    for (int j = 0; j < 8; ++j) dst[j] = f2bf(src[j]);
}

// ---------------------------------------------------------------------------
// k1: grouped input projection x @ w_in -> h_in (bf16). 16 rows/block.
// ---------------------------------------------------------------------------
__global__ __launch_bounds__(256) void k1(const float* __restrict__ x,
                                          const float* __restrict__ w_in,   // [g][i][o]
                                          unsigned short* __restrict__ hin) {
    __shared__ alignas(16) float xt[16][512];
    const int tid  = threadIdx.x;
    const int row0 = blockIdx.x * 16;

    for (int i = tid; i < 16 * 128; i += 256) {
        int rr = i >> 7, c4 = i & 127;
        ((float4*)xt[rr])[c4] =
            ((const float4*)(x + (size_t)(row0 + rr) * 512))[c4];
    }
    __syncthreads();

    for (int q = 0; q < 2; ++q) {
        const int c = tid + (q << 8);
        const int g = c >> 6, o = c & 63;
        const float* wb = w_in + (g << 12) + o;
        float wcol[64];
#pragma unroll
        for (int ii = 0; ii < 64; ++ii) wcol[ii] = wb[ii << 6];
#pragma unroll 4
        for (int rr = 0; rr < 16; ++rr) {
            float acc = 0.f;
#pragma unroll
            for (int ii = 0; ii < 64; ++ii) acc += xt[rr][(g << 6) + ii] * wcol[ii];
            hin[(size_t)(row0 + rr) * 512 + c] = f2bf(acc);
        }
    }
}

// ---------------------------------------------------------------------------
// k2: w_pre = LayerNorm(h_in @ w_rec^T) via MFMA 16x16x32 bf16 (as R7).
// ---------------------------------------------------------------------------
#define ALD 536
__global__ __launch_bounds__(256) void k2(const unsigned short* __restrict__ hin,
                                          const unsigned short* __restrict__ wrt,
                                          const float* __restrict__ gamma,
                                          const float* __restrict__ beta,
                                          float* __restrict__ w_pre) {
    __shared__ alignas(16) unsigned short At[32 * ALD];
    __shared__ float redS[4][32];
    __shared__ float redQ[4][32];
    __shared__ float stat[2][32];

    const int tid  = threadIdx.x;
    const int w    = tid >> 6;
    const int l    = tid & 63;
    const int kgrp = l >> 4;
    const int lc   = l & 15;
    const int row0 = blockIdx.x * 32;

    for (int sidx = tid; sidx < 2048; sidx += 256) {
        int r = sidx >> 6, sg = sidx & 63;
        *(bf16x8*)(At + r * ALD + sg * 8) =
            *(const bf16x8*)(hin + (size_t)(row0 + r) * 512 + sg * 8);
    }
    __syncthreads();

    f32x4 acc[2][16];
#pragma unroll
    for (int fr = 0; fr < 2; ++fr)
#pragma unroll
        for (int n = 0; n < 16; ++n) acc[fr][n] = f32x4{0.f, 0.f, 0.f, 0.f};

    for (int kt = 0; kt < 16; ++kt) {
        bf16x8 a0 = *(const bf16x8*)(At + (lc)      * ALD + kt * 32 + kgrp * 8);
        bf16x8 a1 = *(const bf16x8*)(At + (16 + lc) * ALD + kt * 32 + kgrp * 8);
        const unsigned short* bb =
            wrt + (((size_t)kt * 64 + w * 16) * 64 + l) * 8;
#pragma unroll
        for (int ntl = 0; ntl < 16; ++ntl) {
            bf16x8 bf = *(const bf16x8*)(bb + (size_t)ntl * 512);
            acc[0][ntl] = __builtin_amdgcn_mfma_f32_16x16x32_bf16(a0, bf, acc[0][ntl], 0, 0, 0);
            acc[1][ntl] = __builtin_amdgcn_mfma_f32_16x16x32_bf16(a1, bf, acc[1][ntl], 0, 0, 0);
        }
    }

    float sums[2][4] = {{0.f}}, sqs[2][4] = {{0.f}};
#pragma unroll
    for (int fr = 0; fr < 2; ++fr)
#pragma unroll
        for (int ntl = 0; ntl < 16; ++ntl)
#pragma unroll
            for (int r = 0; r < 4; ++r) {
                float v = acc[fr][ntl][r];
                sums[fr][r] += v;
                sqs[fr][r]  += v * v;
            }
#pragma unroll
    for (int off = 1; off < 16; off <<= 1)
#pragma unroll
        for (int fr = 0; fr < 2; ++fr)
#pragma unroll
            for (int r = 0; r < 4; ++r) {
                sums[fr][r] += __shfl_xor(sums[fr][r], off);
                sqs[fr][r]  += __shfl_xor(sqs[fr][r], off);
            }
    if (lc == 0) {
#pragma unroll
        for (int fr = 0; fr < 2; ++fr)
#pragma unroll
            for (int r = 0; r < 4; ++r) {
                redS[w][fr * 16 + kgrp * 4 + r] = sums[fr][r];
                redQ[w][fr * 16 + kgrp * 4 + r] = sqs[fr][r];
            }
    }
    __syncthreads();
    if (tid < 32) {
        float S = redS[0][tid] + redS[1][tid] + redS[2][tid] + redS[3][tid];
        float Q = redQ[0][tid] + redQ[1][tid] + redQ[2][tid] + redQ[3][tid];
        float mu  = S * (1.f / 1024.f);
        float var = Q * (1.f / 1024.f) - mu * mu;
        stat[0][tid] = mu;
        stat[1][tid] = rsqrtf(var + LN_EPS);
    }
    __syncthreads();

#pragma unroll
    for (int ntl = 0; ntl < 16; ++ntl) {
        const int col = (w << 8) + (ntl << 4) + lc;
        const float g = gamma[col], bt = beta[col];
#pragma unroll
        for (int fr = 0; fr < 2; ++fr)
#pragma unroll
            for (int r = 0; r < 4; ++r) {
                const int row = fr * 16 + kgrp * 4 + r;
                const float mu  = stat[0][row];
                const float inv = stat[1][row];
                w_pre[((size_t)(row0 + row) << 10) + col] =
                    (acc[fr][ntl][r] - mu) * inv * g + bt;
            }
    }
}

// ---------------------------------------------------------------------------
// LiGRU scan: R6 proven structure (2 barriers, gsum LDS, single-wave 256B
// coalesced producer) + 8B stamped polls (verified in R8) + w_pre prefetch
// pipelined one full step ahead (HBM-cold load gets a whole step of slack).
// 8 blocks/batch, dataflow-stamp sync, no fences, no RMW atomics.
// ---------------------------------------------------------------------------
__global__ __launch_bounds__(1024) void k_scan(const float* __restrict__ w_pre,
                                               const float* __restrict__ u,   // [1024][512]
                                               float* __restrict__ hs,        // [B][T][512]
                                               unsigned int* hbuf) {          // [2][32][512]
    __shared__ alignas(16) float hsh[512];
    __shared__ float gsum[128];

    const int tid = threadIdx.x;
    const int b   = blockIdx.x & 31;
    const int s   = blockIdx.x >> 5;
    const int J0  = s << 6;
    const int row = tid >> 3;
    const int kk  = tid & 7;
    const int jj  = (row < 64) ? (J0 + row) : (448 + J0 + row);

    // ---- u slice -> registers (one-time, f32) ----
    float ur[64];
    {
        const float4* up = (const float4*)(u + (size_t)jj * 512 + (kk << 6));
#pragma unroll
        for (int m = 0; m < 16; ++m) {
            float4 v = up[m];
            ur[4 * m + 0] = v.x; ur[4 * m + 1] = v.y;
            ur[4 * m + 2] = v.z; ur[4 * m + 3] = v.w;
        }
    }

    const float* wbase = w_pre + ((size_t)b * T_LEN) * 1024 + jj;
    float* outbase = hs + ((size_t)b * T_LEN) * 512 + J0;
    const char* hb8 = (const char*)hsh;

    float hreg = 0.f;          // own h value (tid < 64)
    float wcur = 0.f;          // w for current step (prefetched 1 step ahead)
    if (kk == 0) wcur = wbase[0];

    for (int t = 0; t < T_LEN; ++t) {
        unsigned int* in_w  = hbuf + ((((t & 1) << 5) | b) << 9);
        unsigned int* out_w = hbuf + (((((t + 1) & 1) << 5) | b) << 9);

        // ---- prefetch NEXT step's w (full step of latency slack) ----
        float wnext = 0.f;
        if (kk == 0 && t + 1 < T_LEN) wnext = wbase[(size_t)(t + 1) << 10];

        // ---- poll (8B, both words stamped) + stage to swizzled LDS ----
        if (tid < 256) {
            const unsigned long long* src = (const unsigned long long*)in_w + tid;
            const unsigned int want = (unsigned)t & 3u;
            unsigned long long v = __hip_atomic_load(src, __ATOMIC_RELAXED,
                                                     __HIP_MEMORY_SCOPE_AGENT);
            while (((unsigned)v & 3u) != want ||
                   ((unsigned)(v >> 32) & 3u) != want) {
                v = __hip_atomic_load(src, __ATOMIC_RELAXED,
                                      __HIP_MEMORY_SCOPE_AGENT);
            }
            int c = tid >> 1;
            int a = (c & ~7) | ((c ^ (c >> 4)) & 7);
            *(unsigned long long*)((char*)hsh + (a << 4) + ((tid & 1) << 3)) = v;
        }
        __syncthreads();

        // ---- dot: 64 f32 MACs via 16 conflict-free float4 LDS reads ----
        float a0 = 0.f, a1 = 0.f, a2 = 0.f, a3 = 0.f;
        const int base = kk << 8;
#pragma unroll
        for (int i = 0; i < 16; ++i) {
            int off = base + (((i & 8) | ((i ^ kk) & 7)) << 4);
            float4 hv = *(const float4*)(hb8 + off);
            a0 += ur[4 * i + 0] * hv.x;
            a1 += ur[4 * i + 1] * hv.y;
            a2 += ur[4 * i + 2] * hv.z;
            a3 += ur[4 * i + 3] * hv.w;
        }
        float acc = (a0 + a1) + (a2 + a3);
        acc += __shfl_xor(acc, 1);
        acc += __shfl_xor(acc, 2);
        acc += __shfl_xor(acc, 4);
        if (kk == 0) gsum[row] = acc + wcur;
        __syncthreads();

        // ---- h update (64 threads): single-wave coalesced 256B stores ----
        if (tid < 64) {
            float a  = gsum[tid];
            float zl = gsum[64 + tid];
            float z  = 1.f / (1.f + __expf(-zl));
            float hn = z * hreg + (1.f - z) * fmaxf(a, 0.f);
            hreg = hn;
            unsigned int bits = (__builtin_bit_cast(unsigned int, hn) & ~3u) |
                                ((unsigned)(t + 1) & 3u);
            __hip_atomic_store(out_w + J0 + tid, bits, __ATOMIC_RELAXED,
                               __HIP_MEMORY_SCOPE_AGENT);
            outbase[((size_t)t << 9) + tid] = hn;
        }
        wcur = wnext;
        // no 3rd barrier: hsh re-staging for t+1 is gated by the t+1 poll,
        // which cannot pass until this block's own producers store stamp t+1
        // (they do so only after reading gsum post-barrier#2).
    }
}

// ---------------------------------------------------------------------------
// Output grouped linear, in-place on d_out (holds hs after k_scan).
// ---------------------------------------------------------------------------
__global__ __launch_bounds__(256) void k_out(const float* __restrict__ w_out, // [g][i][o]
                                             float* __restrict__ io) {
    __shared__ alignas(16) float ht[8][512];
    const int tid  = threadIdx.x;
    const int row0 = blockIdx.x * 8;

    for (int i = tid; i < 8 * 128; i += 256) {
        int rr = i >> 7, c4 = i & 127;
        ((float4*)ht[rr])[c4] =
            ((const float4*)(io + (size_t)(row0 + rr) * 512))[c4];
    }
    __syncthreads();

    for (int q = 0; q < 2; ++q) {
        const int c = tid + (q << 8);
        const int g = c >> 6, o = c & 63;
        const float* wb = w_out + (g << 12) + o;
        float wcol[64];
#pragma unroll
        for (int ii = 0; ii < 64; ++ii) wcol[ii] = wb[ii << 6];
#pragma unroll 4
        for (int rr = 0; rr < 8; ++rr) {
            float acc = 0.f;
#pragma unroll
            for (int ii = 0; ii < 64; ++ii) acc += ht[rr][(g << 6) + ii] * wcol[ii];
            io[(size_t)(row0 + rr) * 512 + c] = acc;
        }
    }
}

// ---------------------------------------------------------------------------
extern "C" void kernel_launch(void* const* d_in, const int* in_sizes, int n_in,
                              void* d_out, int out_size, void* d_ws, size_t ws_size,
                              hipStream_t stream) {
    const float* x      = (const float*)d_in[0];
    const float* w_in   = (const float*)d_in[1];
    const float* w_rec  = (const float*)d_in[2];
    const float* u_rec  = (const float*)d_in[3];
    const float* gamma  = (const float*)d_in[4];
    const float* beta   = (const float*)d_in[5];
    const float* w_out  = (const float*)d_in[6];
    float* out = (float*)d_out;

    // workspace layout (131,203,072 B — proven bound)
    float*        w_pre = (float*)d_ws;                       // 32,768,000 f32
    unsigned int* hbuf  = (unsigned int*)(w_pre + (size_t)32 * T_LEN * 1024); // [2][32][512]

    // d_out staging (dead until k_scan overwrites it)
    unsigned short* hin = (unsigned short*)d_out;
    unsigned short* wrt = hin + (size_t)32000 * 512;

    hipLaunchKernelGGL(kw, dim3(256), dim3(256), 0, stream, w_rec, wrt);
    hipLaunchKernelGGL(k1, dim3(2000), dim3(256), 0, stream, x, w_in, hin);
    hipLaunchKernelGGL(k2, dim3(1000), dim3(256), 0, stream,
                       hin, wrt, gamma, beta, w_pre);
    hipMemsetAsync(hbuf, 0, 2 * 32 * 512 * sizeof(unsigned int), stream);
    hipLaunchKernelGGL(k_scan, dim3(256), dim3(1024), 0, stream,
                       w_pre, u_rec, out, hbuf);
    hipLaunchKernelGGL(k_out, dim3(4000), dim3(256), 0, stream, w_out, out);
}

// Round 12
// 1661.085 us; speedup vs baseline: 3.4639x; 1.1477x over previous
//
#include <hip/hip_runtime.h>
#include <cstddef>

#define B_SZ 32
#define T_LEN 1000
#define LN_EPS 1e-5f

typedef short bf16x8 __attribute__((ext_vector_type(8)));
typedef float f32x4 __attribute__((ext_vector_type(4)));

__device__ __forceinline__ unsigned short f2bf(float f) {
    unsigned u = __builtin_bit_cast(unsigned, f);
    u += 0x7FFFu + ((u >> 16) & 1u);          // RNE
    return (unsigned short)(u >> 16);
}

// ---------------------------------------------------------------------------
// k1: grouped input projection x @ w_in -> h_in (bf16). 16 rows/block.
// Piggybacked (blocks 0..255): pack w_rec into bf16 MFMA B-fragments (wrt);
// blocks 0..127: zero hbuf (replaces the hipMemsetAsync node).
// ---------------------------------------------------------------------------
__global__ __launch_bounds__(256) void k1(const float* __restrict__ x,
                                          const float* __restrict__ w_in,   // [g][i][o]
                                          const float* __restrict__ w_rec,  // [1024][512]
                                          unsigned short* __restrict__ hin,
                                          unsigned short* __restrict__ wrt,
                                          unsigned int* __restrict__ hbuf) {
    __shared__ alignas(16) float xt[16][512];
    const int tid  = threadIdx.x;
    const int gidx = blockIdx.x * 256 + tid;
    const int row0 = blockIdx.x * 16;

    // ---- piggyback: zero stamped h exchange buffer ----
    if (gidx < 2 * 32 * 512) hbuf[gidx] = 0u;

    // ---- piggyback: pack w_rec fragments (65536 thread-slots) ----
    if (gidx < 65536) {
        int lane = gidx & 63;
        int nt   = (gidx >> 6) & 63;
        int kt   = gidx >> 12;
        int n    = nt * 16 + (lane & 15);
        int k0   = kt * 32 + (lane >> 4) * 8;
        const float* src = w_rec + (size_t)n * 512 + k0;
        unsigned short* dst = wrt + (size_t)gidx * 8;
#pragma unroll
        for (int j = 0; j < 8; ++j) dst[j] = f2bf(src[j]);
    }

    // ---- load 16 x-rows into LDS (float4, coalesced) ----
    for (int i = tid; i < 16 * 128; i += 256) {
        int rr = i >> 7, c4 = i & 127;
        ((float4*)xt[rr])[c4] =
            ((const float4*)(x + (size_t)(row0 + rr) * 512))[c4];
    }
    __syncthreads();

    for (int q = 0; q < 2; ++q) {
        const int c = tid + (q << 8);
        const int g = c >> 6, o = c & 63;
        const float* wb = w_in + (g << 12) + o;
        float wcol[64];
#pragma unroll
        for (int ii = 0; ii < 64; ++ii) wcol[ii] = wb[ii << 6];
#pragma unroll 4
        for (int rr = 0; rr < 16; ++rr) {
            float acc = 0.f;
#pragma unroll
            for (int ii = 0; ii < 64; ++ii) acc += xt[rr][(g << 6) + ii] * wcol[ii];
            hin[(size_t)(row0 + rr) * 512 + c] = f2bf(acc);
        }
    }
}

// ---------------------------------------------------------------------------
// k2: w_pre = LayerNorm(h_in @ w_rec^T) via MFMA 16x16x32 bf16 (proven R7).
// ---------------------------------------------------------------------------
#define ALD 536
__global__ __launch_bounds__(256) void k2(const unsigned short* __restrict__ hin,
                                          const unsigned short* __restrict__ wrt,
                                          const float* __restrict__ gamma,
                                          const float* __restrict__ beta,
                                          float* __restrict__ w_pre) {
    __shared__ alignas(16) unsigned short At[32 * ALD];
    __shared__ float redS[4][32];
    __shared__ float redQ[4][32];
    __shared__ float stat[2][32];

    const int tid  = threadIdx.x;
    const int w    = tid >> 6;
    const int l    = tid & 63;
    const int kgrp = l >> 4;
    const int lc   = l & 15;
    const int row0 = blockIdx.x * 32;

    for (int sidx = tid; sidx < 2048; sidx += 256) {
        int r = sidx >> 6, sg = sidx & 63;
        *(bf16x8*)(At + r * ALD + sg * 8) =
            *(const bf16x8*)(hin + (size_t)(row0 + r) * 512 + sg * 8);
    }
    __syncthreads();

    f32x4 acc[2][16];
#pragma unroll
    for (int fr = 0; fr < 2; ++fr)
#pragma unroll
        for (int n = 0; n < 16; ++n) acc[fr][n] = f32x4{0.f, 0.f, 0.f, 0.f};

    for (int kt = 0; kt < 16; ++kt) {
        bf16x8 a0 = *(const bf16x8*)(At + (lc)      * ALD + kt * 32 + kgrp * 8);
        bf16x8 a1 = *(const bf16x8*)(At + (16 + lc) * ALD + kt * 32 + kgrp * 8);
        const unsigned short* bb =
            wrt + (((size_t)kt * 64 + w * 16) * 64 + l) * 8;
#pragma unroll
        for (int ntl = 0; ntl < 16; ++ntl) {
            bf16x8 bf = *(const bf16x8*)(bb + (size_t)ntl * 512);
            acc[0][ntl] = __builtin_amdgcn_mfma_f32_16x16x32_bf16(a0, bf, acc[0][ntl], 0, 0, 0);
            acc[1][ntl] = __builtin_amdgcn_mfma_f32_16x16x32_bf16(a1, bf, acc[1][ntl], 0, 0, 0);
        }
    }

    float sums[2][4] = {{0.f}}, sqs[2][4] = {{0.f}};
#pragma unroll
    for (int fr = 0; fr < 2; ++fr)
#pragma unroll
        for (int ntl = 0; ntl < 16; ++ntl)
#pragma unroll
            for (int r = 0; r < 4; ++r) {
                float v = acc[fr][ntl][r];
                sums[fr][r] += v;
                sqs[fr][r]  += v * v;
            }
#pragma unroll
    for (int off = 1; off < 16; off <<= 1)
#pragma unroll
        for (int fr = 0; fr < 2; ++fr)
#pragma unroll
            for (int r = 0; r < 4; ++r) {
                sums[fr][r] += __shfl_xor(sums[fr][r], off);
                sqs[fr][r]  += __shfl_xor(sqs[fr][r], off);
            }
    if (lc == 0) {
#pragma unroll
        for (int fr = 0; fr < 2; ++fr)
#pragma unroll
            for (int r = 0; r < 4; ++r) {
                redS[w][fr * 16 + kgrp * 4 + r] = sums[fr][r];
                redQ[w][fr * 16 + kgrp * 4 + r] = sqs[fr][r];
            }
    }
    __syncthreads();
    if (tid < 32) {
        float S = redS[0][tid] + redS[1][tid] + redS[2][tid] + redS[3][tid];
        float Q = redQ[0][tid] + redQ[1][tid] + redQ[2][tid] + redQ[3][tid];
        float mu  = S * (1.f / 1024.f);
        float var = Q * (1.f / 1024.f) - mu * mu;
        stat[0][tid] = mu;
        stat[1][tid] = rsqrtf(var + LN_EPS);
    }
    __syncthreads();

#pragma unroll
    for (int ntl = 0; ntl < 16; ++ntl) {
        const int col = (w << 8) + (ntl << 4) + lc;
        const float g = gamma[col], bt = beta[col];
#pragma unroll
        for (int fr = 0; fr < 2; ++fr)
#pragma unroll
            for (int r = 0; r < 4; ++r) {
                const int row = fr * 16 + kgrp * 4 + r;
                const float mu  = stat[0][row];
                const float inv = stat[1][row];
                w_pre[((size_t)(row0 + row) << 10) + col] =
                    (acc[fr][ntl][r] - mu) * inv * g + bt;
            }
    }
}

// ---------------------------------------------------------------------------
// LiGRU scan: BYTE-IDENTICAL to R9's proven-pass version (1490 µs).
// f16 banned (R3/R10: absmax 2.51); early-poll banned (R11: post-timing race).
// ---------------------------------------------------------------------------
__global__ __launch_bounds__(1024) void k_scan(const float* __restrict__ w_pre,
                                               const float* __restrict__ u,   // [1024][512]
                                               float* __restrict__ hs,        // [B][T][512]
                                               unsigned int* hbuf) {          // [2][32][512]
    __shared__ alignas(16) float hsh[512];
    __shared__ float gsum[128];

    const int tid = threadIdx.x;
    const int b   = blockIdx.x & 31;
    const int s   = blockIdx.x >> 5;
    const int J0  = s << 6;
    const int row = tid >> 3;
    const int kk  = tid & 7;
    const int jj  = (row < 64) ? (J0 + row) : (448 + J0 + row);

    // ---- u slice -> registers (one-time, f32) ----
    float ur[64];
    {
        const float4* up = (const float4*)(u + (size_t)jj * 512 + (kk << 6));
#pragma unroll
        for (int m = 0; m < 16; ++m) {
            float4 v = up[m];
            ur[4 * m + 0] = v.x; ur[4 * m + 1] = v.y;
            ur[4 * m + 2] = v.z; ur[4 * m + 3] = v.w;
        }
    }

    const float* wbase = w_pre + ((size_t)b * T_LEN) * 1024 + jj;
    float* outbase = hs + ((size_t)b * T_LEN) * 512 + J0;
    const char* hb8 = (const char*)hsh;

    float hreg = 0.f;          // own h value (tid < 64)
    float wcur = 0.f;          // w for current step (prefetched 1 step ahead)
    if (kk == 0) wcur = wbase[0];

    for (int t = 0; t < T_LEN; ++t) {
        unsigned int* in_w  = hbuf + ((((t & 1) << 5) | b) << 9);
        unsigned int* out_w = hbuf + (((((t + 1) & 1) << 5) | b) << 9);

        // ---- prefetch NEXT step's w (full step of latency slack) ----
        float wnext = 0.f;
        if (kk == 0 && t + 1 < T_LEN) wnext = wbase[(size_t)(t + 1) << 10];

        // ---- poll (8B, both words stamped) + stage to swizzled LDS ----
        if (tid < 256) {
            const unsigned long long* src = (const unsigned long long*)in_w + tid;
            const unsigned int want = (unsigned)t & 3u;
            unsigned long long v = __hip_atomic_load(src, __ATOMIC_RELAXED,
                                                     __HIP_MEMORY_SCOPE_AGENT);
            while (((unsigned)v & 3u) != want ||
                   ((unsigned)(v >> 32) & 3u) != want) {
                v = __hip_atomic_load(src, __ATOMIC_RELAXED,
                                      __HIP_MEMORY_SCOPE_AGENT);
            }
            int c = tid >> 1;
            int a = (c & ~7) | ((c ^ (c >> 4)) & 7);
            *(unsigned long long*)((char*)hsh + (a << 4) + ((tid & 1) << 3)) = v;
        }
        __syncthreads();

        // ---- dot: 64 f32 MACs via 16 conflict-free float4 LDS reads ----
        float a0 = 0.f, a1 = 0.f, a2 = 0.f, a3 = 0.f;
        const int base = kk << 8;
#pragma unroll
        for (int i = 0; i < 16; ++i) {
            int off = base + (((i & 8) | ((i ^ kk) & 7)) << 4);
            float4 hv = *(const float4*)(hb8 + off);
            a0 += ur[4 * i + 0] * hv.x;
            a1 += ur[4 * i + 1] * hv.y;
            a2 += ur[4 * i + 2] * hv.z;
            a3 += ur[4 * i + 3] * hv.w;
        }
        float acc = (a0 + a1) + (a2 + a3);
        acc += __shfl_xor(acc, 1);
        acc += __shfl_xor(acc, 2);
        acc += __shfl_xor(acc, 4);
        if (kk == 0) gsum[row] = acc + wcur;
        __syncthreads();

        // ---- h update (64 threads): single-wave coalesced 256B stores ----
        if (tid < 64) {
            float a  = gsum[tid];
            float zl = gsum[64 + tid];
            float z  = 1.f / (1.f + __expf(-zl));
            float hn = z * hreg + (1.f - z) * fmaxf(a, 0.f);
            hreg = hn;
            unsigned int bits = (__builtin_bit_cast(unsigned int, hn) & ~3u) |
                                ((unsigned)(t + 1) & 3u);
            __hip_atomic_store(out_w + J0 + tid, bits, __ATOMIC_RELAXED,
                               __HIP_MEMORY_SCOPE_AGENT);
            outbase[((size_t)t << 9) + tid] = hn;
        }
        wcur = wnext;
        // no 3rd barrier: hsh re-staging for t+1 is gated by the t+1 poll,
        // which cannot pass until this block's producers store stamp t+1
        // (after their gsum reads post-barrier#2).
    }
}

// ---------------------------------------------------------------------------
// k_out: grouped output linear via MFMA 16x16x32 bf16, in-place on d_out.
// Block = 32 rows x 512 cols. Wave w -> groups 2w, 2w+1 (128 cols).
// A: h rows staged f32->bf16 into k2's proven padded-LDS layout.
// B: fragments built in-registers from L2-resident w_out (f32, 8 strided
//    loads + f2bf per frag). D layout: col=lane&15, row=(lane>>4)*4+reg.
// In-place safe: all io reads staged before the barrier, writes after.
// ---------------------------------------------------------------------------
__global__ __launch_bounds__(256) void k_out(const float* __restrict__ w_out, // [g][i][o]
                                             float* __restrict__ io) {
    __shared__ alignas(16) unsigned short At[32 * ALD];

    const int tid  = threadIdx.x;
    const int w    = tid >> 6;
    const int l    = tid & 63;
    const int kgrp = l >> 4;
    const int lc   = l & 15;
    const int row0 = blockIdx.x * 32;

    // ---- stage 32 rows x 512 f32 -> bf16 padded LDS ----
    for (int sidx = tid; sidx < 2048; sidx += 256) {
        int r = sidx >> 6, c8 = sidx & 63;
        const float4* src = (const float4*)(io + (size_t)(row0 + r) * 512 + c8 * 8);
        float4 v0 = src[0], v1 = src[1];
        unsigned short tmp[8] = {f2bf(v0.x), f2bf(v0.y), f2bf(v0.z), f2bf(v0.w),
                                 f2bf(v1.x), f2bf(v1.y), f2bf(v1.z), f2bf(v1.w)};
        *(bf16x8*)(At + r * ALD + c8 * 8) = *(bf16x8*)tmp;
    }
    __syncthreads();

    // ---- B fragments for this wave's 2 groups (16 frags, from L2) ----
    bf16x8 bfr[16];
#pragma unroll
    for (int gi = 0; gi < 2; ++gi) {
        const int g = 2 * w + gi;
#pragma unroll
        for (int kt = 0; kt < 2; ++kt) {
            const float* bsrc = w_out + (g << 12) + (kt * 32 + kgrp * 8) * 64 + lc;
#pragma unroll
            for (int nt = 0; nt < 4; ++nt) {
                unsigned short bw[8];
#pragma unroll
                for (int j = 0; j < 8; ++j) bw[j] = f2bf(bsrc[j * 64 + nt * 16]);
                bfr[(gi * 2 + kt) * 4 + nt] = *(bf16x8*)bw;
            }
        }
    }

    // ---- MFMA: 32 per wave ----
    f32x4 acc[2][8];
#pragma unroll
    for (int fr = 0; fr < 2; ++fr)
#pragma unroll
        for (int n = 0; n < 8; ++n) acc[fr][n] = f32x4{0.f, 0.f, 0.f, 0.f};

#pragma unroll
    for (int gi = 0; gi < 2; ++gi) {
        const int g = 2 * w + gi;
#pragma unroll
        for (int kt = 0; kt < 2; ++kt) {
            bf16x8 a0 = *(const bf16x8*)(At + lc        * ALD + g * 64 + kt * 32 + kgrp * 8);
            bf16x8 a1 = *(const bf16x8*)(At + (16 + lc) * ALD + g * 64 + kt * 32 + kgrp * 8);
#pragma unroll
            for (int nt = 0; nt < 4; ++nt) {
                bf16x8 bf = bfr[(gi * 2 + kt) * 4 + nt];
                acc[0][gi * 4 + nt] = __builtin_amdgcn_mfma_f32_16x16x32_bf16(a0, bf, acc[0][gi * 4 + nt], 0, 0, 0);
                acc[1][gi * 4 + nt] = __builtin_amdgcn_mfma_f32_16x16x32_bf16(a1, bf, acc[1][gi * 4 + nt], 0, 0, 0);
            }
        }
    }

    // ---- store (in-place; reads all done pre-barrier) ----
#pragma unroll
    for (int gi = 0; gi < 2; ++gi)
#pragma unroll
        for (int nt = 0; nt < 4; ++nt) {
            const int col = (2 * w + gi) * 64 + nt * 16 + lc;
#pragma unroll
            for (int fr = 0; fr < 2; ++fr)
#pragma unroll
                for (int r = 0; r < 4; ++r)
                    io[(size_t)(row0 + fr * 16 + kgrp * 4 + r) * 512 + col] =
                        acc[fr][gi * 4 + nt][r];
        }
}

// ---------------------------------------------------------------------------
extern "C" void kernel_launch(void* const* d_in, const int* in_sizes, int n_in,
                              void* d_out, int out_size, void* d_ws, size_t ws_size,
                              hipStream_t stream) {
    const float* x      = (const float*)d_in[0];
    const float* w_in   = (const float*)d_in[1];
    const float* w_rec  = (const float*)d_in[2];
    const float* u_rec  = (const float*)d_in[3];
    const float* gamma  = (const float*)d_in[4];
    const float* beta   = (const float*)d_in[5];
    const float* w_out  = (const float*)d_in[6];
    float* out = (float*)d_out;

    // workspace layout (131,203,072 B — proven bound)
    float*        w_pre = (float*)d_ws;                       // 32,768,000 f32
    unsigned int* hbuf  = (unsigned int*)(w_pre + (size_t)32 * T_LEN * 1024); // [2][32][512]

    // d_out staging (dead until k_scan overwrites it)
    unsigned short* hin = (unsigned short*)d_out;
    unsigned short* wrt = hin + (size_t)32000 * 512;

    hipLaunchKernelGGL(k1, dim3(2000), dim3(256), 0, stream,
                       x, w_in, w_rec, hin, wrt, hbuf);
    hipLaunchKernelGGL(k2, dim3(1000), dim3(256), 0, stream,
                       hin, wrt, gamma, beta, w_pre);
    hipLaunchKernelGGL(k_scan, dim3(256), dim3(1024), 0, stream,
                       w_pre, u_rec, out, hbuf);
    hipLaunchKernelGGL(k_out, dim3(1000), dim3(256), 0, stream, w_out, out);
}

// Round 13
// 1624.696 us; speedup vs baseline: 3.5415x; 1.0224x over previous
//
#include <hip/hip_runtime.h>
#include <cstddef>

#define B_SZ 32
#define T_LEN 1000
#define LN_EPS 1e-5f
#define ALD 536   // padded bf16 LDS leading dim (512+24): conflict-free frags

typedef short bf16x8 __attribute__((ext_vector_type(8)));
typedef float f32x4 __attribute__((ext_vector_type(4)));

__device__ __forceinline__ unsigned short f2bf(float f) {
    unsigned u = __builtin_bit_cast(unsigned, f);
    u += 0x7FFFu + ((u >> 16) & 1u);          // RNE
    return (unsigned short)(u >> 16);
}

// ---------------------------------------------------------------------------
// k1: grouped input projection x @ w_in -> h_in (bf16) via MFMA 16x16x32.
// Block = 32 rows x 512 cols (8 diag groups of 64x64), 256 threads / 4 waves.
// Wave w -> groups 2w, 2w+1. A: x staged f32->bf16 padded LDS (k_out-proven
// pattern). B: frags built in-registers from L2-resident w_in (k_out-proven
// pattern). D: routed through LDS (2-way-conflict u16 writes = free), then
// coalesced bf16x8 stores to hin.
// Piggybacked: blocks 0..255 pack w_rec into MFMA B-frags (wrt); blocks
// 0..127 zero hbuf (replaces memset node).
// ---------------------------------------------------------------------------
__global__ __launch_bounds__(256) void k1(const float* __restrict__ x,
                                          const float* __restrict__ w_in,   // [g][i][o]
                                          const float* __restrict__ w_rec,  // [1024][512]
                                          unsigned short* __restrict__ hin,
                                          unsigned short* __restrict__ wrt,
                                          unsigned int* __restrict__ hbuf) {
    __shared__ alignas(16) unsigned short At[32 * ALD];

    const int tid  = threadIdx.x;
    const int gidx = blockIdx.x * 256 + tid;
    const int w    = tid >> 6;
    const int l    = tid & 63;
    const int kgrp = l >> 4;
    const int lc   = l & 15;
    const int row0 = blockIdx.x * 32;

    // ---- piggyback: zero stamped h exchange buffer ----
    if (gidx < 2 * 32 * 512) hbuf[gidx] = 0u;

    // ---- piggyback: pack w_rec fragments (65536 thread-slots) ----
    if (gidx < 65536) {
        int lane = gidx & 63;
        int nt   = (gidx >> 6) & 63;
        int kt   = gidx >> 12;
        int n    = nt * 16 + (lane & 15);
        int k0   = kt * 32 + (lane >> 4) * 8;
        const float* src = w_rec + (size_t)n * 512 + k0;
        unsigned short* dst = wrt + (size_t)gidx * 8;
#pragma unroll
        for (int j = 0; j < 8; ++j) dst[j] = f2bf(src[j]);
    }

    // ---- stage x: 32 rows x 512 f32 -> bf16 padded LDS ----
    for (int sidx = tid; sidx < 2048; sidx += 256) {
        int r = sidx >> 6, c8 = sidx & 63;
        const float4* src = (const float4*)(x + (size_t)(row0 + r) * 512 + c8 * 8);
        float4 v0 = src[0], v1 = src[1];
        unsigned short tmp[8] = {f2bf(v0.x), f2bf(v0.y), f2bf(v0.z), f2bf(v0.w),
                                 f2bf(v1.x), f2bf(v1.y), f2bf(v1.z), f2bf(v1.w)};
        *(bf16x8*)(At + r * ALD + c8 * 8) = *(bf16x8*)tmp;
    }
    __syncthreads();

    // ---- B fragments for this wave's 2 groups (16 frags, from L2) ----
    bf16x8 bfr[16];
#pragma unroll
    for (int gi = 0; gi < 2; ++gi) {
        const int g = 2 * w + gi;
#pragma unroll
        for (int kt = 0; kt < 2; ++kt) {
            const float* bsrc = w_in + (g << 12) + (kt * 32 + kgrp * 8) * 64 + lc;
#pragma unroll
            for (int nt = 0; nt < 4; ++nt) {
                unsigned short bw[8];
#pragma unroll
                for (int j = 0; j < 8; ++j) bw[j] = f2bf(bsrc[j * 64 + nt * 16]);
                bfr[(gi * 2 + kt) * 4 + nt] = *(bf16x8*)bw;
            }
        }
    }

    // ---- MFMA: 32 per wave ----
    f32x4 acc[2][8];
#pragma unroll
    for (int fr = 0; fr < 2; ++fr)
#pragma unroll
        for (int n = 0; n < 8; ++n) acc[fr][n] = f32x4{0.f, 0.f, 0.f, 0.f};

#pragma unroll
    for (int gi = 0; gi < 2; ++gi) {
        const int g = 2 * w + gi;
#pragma unroll
        for (int kt = 0; kt < 2; ++kt) {
            bf16x8 a0 = *(const bf16x8*)(At + lc        * ALD + g * 64 + kt * 32 + kgrp * 8);
            bf16x8 a1 = *(const bf16x8*)(At + (16 + lc) * ALD + g * 64 + kt * 32 + kgrp * 8);
#pragma unroll
            for (int nt = 0; nt < 4; ++nt) {
                bf16x8 bf = bfr[(gi * 2 + kt) * 4 + nt];
                acc[0][gi * 4 + nt] = __builtin_amdgcn_mfma_f32_16x16x32_bf16(a0, bf, acc[0][gi * 4 + nt], 0, 0, 0);
                acc[1][gi * 4 + nt] = __builtin_amdgcn_mfma_f32_16x16x32_bf16(a1, bf, acc[1][gi * 4 + nt], 0, 0, 0);
            }
        }
    }
    __syncthreads();   // x reads done; At reused for D

    // ---- D -> LDS bf16 (row = fr*16+kgrp*4+r, col = group*64+nt*16+lc) ----
#pragma unroll
    for (int gi = 0; gi < 2; ++gi)
#pragma unroll
        for (int nt = 0; nt < 4; ++nt) {
            const int col = (2 * w + gi) * 64 + nt * 16 + lc;
#pragma unroll
            for (int fr = 0; fr < 2; ++fr)
#pragma unroll
                for (int r = 0; r < 4; ++r)
                    At[(fr * 16 + kgrp * 4 + r) * ALD + col] =
                        f2bf(acc[fr][gi * 4 + nt][r]);
        }
    __syncthreads();

    // ---- coalesced LDS -> global hin (bf16x8) ----
    for (int sidx = tid; sidx < 2048; sidx += 256) {
        int r = sidx >> 6, c8 = sidx & 63;
        *(bf16x8*)(hin + (size_t)(row0 + r) * 512 + c8 * 8) =
            *(const bf16x8*)(At + r * ALD + c8 * 8);
    }
}

// ---------------------------------------------------------------------------
// k2: w_pre = LayerNorm(h_in @ w_rec^T) via MFMA 16x16x32 bf16 (proven R7).
// ---------------------------------------------------------------------------
__global__ __launch_bounds__(256) void k2(const unsigned short* __restrict__ hin,
                                          const unsigned short* __restrict__ wrt,
                                          const float* __restrict__ gamma,
                                          const float* __restrict__ beta,
                                          float* __restrict__ w_pre) {
    __shared__ alignas(16) unsigned short At[32 * ALD];
    __shared__ float redS[4][32];
    __shared__ float redQ[4][32];
    __shared__ float stat[2][32];

    const int tid  = threadIdx.x;
    const int w    = tid >> 6;
    const int l    = tid & 63;
    const int kgrp = l >> 4;
    const int lc   = l & 15;
    const int row0 = blockIdx.x * 32;

    for (int sidx = tid; sidx < 2048; sidx += 256) {
        int r = sidx >> 6, sg = sidx & 63;
        *(bf16x8*)(At + r * ALD + sg * 8) =
            *(const bf16x8*)(hin + (size_t)(row0 + r) * 512 + sg * 8);
    }
    __syncthreads();

    f32x4 acc[2][16];
#pragma unroll
    for (int fr = 0; fr < 2; ++fr)
#pragma unroll
        for (int n = 0; n < 16; ++n) acc[fr][n] = f32x4{0.f, 0.f, 0.f, 0.f};

    for (int kt = 0; kt < 16; ++kt) {
        bf16x8 a0 = *(const bf16x8*)(At + (lc)      * ALD + kt * 32 + kgrp * 8);
        bf16x8 a1 = *(const bf16x8*)(At + (16 + lc) * ALD + kt * 32 + kgrp * 8);
        const unsigned short* bb =
            wrt + (((size_t)kt * 64 + w * 16) * 64 + l) * 8;
#pragma unroll
        for (int ntl = 0; ntl < 16; ++ntl) {
            bf16x8 bf = *(const bf16x8*)(bb + (size_t)ntl * 512);
            acc[0][ntl] = __builtin_amdgcn_mfma_f32_16x16x32_bf16(a0, bf, acc[0][ntl], 0, 0, 0);
            acc[1][ntl] = __builtin_amdgcn_mfma_f32_16x16x32_bf16(a1, bf, acc[1][ntl], 0, 0, 0);
        }
    }

    float sums[2][4] = {{0.f}}, sqs[2][4] = {{0.f}};
#pragma unroll
    for (int fr = 0; fr < 2; ++fr)
#pragma unroll
        for (int ntl = 0; ntl < 16; ++ntl)
#pragma unroll
            for (int r = 0; r < 4; ++r) {
                float v = acc[fr][ntl][r];
                sums[fr][r] += v;
                sqs[fr][r]  += v * v;
            }
#pragma unroll
    for (int off = 1; off < 16; off <<= 1)
#pragma unroll
        for (int fr = 0; fr < 2; ++fr)
#pragma unroll
            for (int r = 0; r < 4; ++r) {
                sums[fr][r] += __shfl_xor(sums[fr][r], off);
                sqs[fr][r]  += __shfl_xor(sqs[fr][r], off);
            }
    if (lc == 0) {
#pragma unroll
        for (int fr = 0; fr < 2; ++fr)
#pragma unroll
            for (int r = 0; r < 4; ++r) {
                redS[w][fr * 16 + kgrp * 4 + r] = sums[fr][r];
                redQ[w][fr * 16 + kgrp * 4 + r] = sqs[fr][r];
            }
    }
    __syncthreads();
    if (tid < 32) {
        float S = redS[0][tid] + redS[1][tid] + redS[2][tid] + redS[3][tid];
        float Q = redQ[0][tid] + redQ[1][tid] + redQ[2][tid] + redQ[3][tid];
        float mu  = S * (1.f / 1024.f);
        float var = Q * (1.f / 1024.f) - mu * mu;
        stat[0][tid] = mu;
        stat[1][tid] = rsqrtf(var + LN_EPS);
    }
    __syncthreads();

#pragma unroll
    for (int ntl = 0; ntl < 16; ++ntl) {
        const int col = (w << 8) + (ntl << 4) + lc;
        const float g = gamma[col], bt = beta[col];
#pragma unroll
        for (int fr = 0; fr < 2; ++fr)
#pragma unroll
            for (int r = 0; r < 4; ++r) {
                const int row = fr * 16 + kgrp * 4 + r;
                const float mu  = stat[0][row];
                const float inv = stat[1][row];
                w_pre[((size_t)(row0 + row) << 10) + col] =
                    (acc[fr][ntl][r] - mu) * inv * g + bt;
            }
    }
}

// ---------------------------------------------------------------------------
// LiGRU scan: BYTE-IDENTICAL to R9/R12's proven-pass version (~1490 µs).
// f16 banned (R3/R10: absmax 2.51); early-poll banned (R11: post-timing race).
// ---------------------------------------------------------------------------
__global__ __launch_bounds__(1024) void k_scan(const float* __restrict__ w_pre,
                                               const float* __restrict__ u,   // [1024][512]
                                               float* __restrict__ hs,        // [B][T][512]
                                               unsigned int* hbuf) {          // [2][32][512]
    __shared__ alignas(16) float hsh[512];
    __shared__ float gsum[128];

    const int tid = threadIdx.x;
    const int b   = blockIdx.x & 31;
    const int s   = blockIdx.x >> 5;
    const int J0  = s << 6;
    const int row = tid >> 3;
    const int kk  = tid & 7;
    const int jj  = (row < 64) ? (J0 + row) : (448 + J0 + row);

    // ---- u slice -> registers (one-time, f32) ----
    float ur[64];
    {
        const float4* up = (const float4*)(u + (size_t)jj * 512 + (kk << 6));
#pragma unroll
        for (int m = 0; m < 16; ++m) {
            float4 v = up[m];
            ur[4 * m + 0] = v.x; ur[4 * m + 1] = v.y;
            ur[4 * m + 2] = v.z; ur[4 * m + 3] = v.w;
        }
    }

    const float* wbase = w_pre + ((size_t)b * T_LEN) * 1024 + jj;
    float* outbase = hs + ((size_t)b * T_LEN) * 512 + J0;
    const char* hb8 = (const char*)hsh;

    float hreg = 0.f;          // own h value (tid < 64)
    float wcur = 0.f;          // w for current step (prefetched 1 step ahead)
    if (kk == 0) wcur = wbase[0];

    for (int t = 0; t < T_LEN; ++t) {
        unsigned int* in_w  = hbuf + ((((t & 1) << 5) | b) << 9);
        unsigned int* out_w = hbuf + (((((t + 1) & 1) << 5) | b) << 9);

        // ---- prefetch NEXT step's w (full step of latency slack) ----
        float wnext = 0.f;
        if (kk == 0 && t + 1 < T_LEN) wnext = wbase[(size_t)(t + 1) << 10];

        // ---- poll (8B, both words stamped) + stage to swizzled LDS ----
        if (tid < 256) {
            const unsigned long long* src = (const unsigned long long*)in_w + tid;
            const unsigned int want = (unsigned)t & 3u;
            unsigned long long v = __hip_atomic_load(src, __ATOMIC_RELAXED,
                                                     __HIP_MEMORY_SCOPE_AGENT);
            while (((unsigned)v & 3u) != want ||
                   ((unsigned)(v >> 32) & 3u) != want) {
                v = __hip_atomic_load(src, __ATOMIC_RELAXED,
                                      __HIP_MEMORY_SCOPE_AGENT);
            }
            int c = tid >> 1;
            int a = (c & ~7) | ((c ^ (c >> 4)) & 7);
            *(unsigned long long*)((char*)hsh + (a << 4) + ((tid & 1) << 3)) = v;
        }
        __syncthreads();

        // ---- dot: 64 f32 MACs via 16 conflict-free float4 LDS reads ----
        float a0 = 0.f, a1 = 0.f, a2 = 0.f, a3 = 0.f;
        const int base = kk << 8;
#pragma unroll
        for (int i = 0; i < 16; ++i) {
            int off = base + (((i & 8) | ((i ^ kk) & 7)) << 4);
            float4 hv = *(const float4*)(hb8 + off);
            a0 += ur[4 * i + 0] * hv.x;
            a1 += ur[4 * i + 1] * hv.y;
            a2 += ur[4 * i + 2] * hv.z;
            a3 += ur[4 * i + 3] * hv.w;
        }
        float acc = (a0 + a1) + (a2 + a3);
        acc += __shfl_xor(acc, 1);
        acc += __shfl_xor(acc, 2);
        acc += __shfl_xor(acc, 4);
        if (kk == 0) gsum[row] = acc + wcur;
        __syncthreads();

        // ---- h update (64 threads): single-wave coalesced 256B stores ----
        if (tid < 64) {
            float a  = gsum[tid];
            float zl = gsum[64 + tid];
            float z  = 1.f / (1.f + __expf(-zl));
            float hn = z * hreg + (1.f - z) * fmaxf(a, 0.f);
            hreg = hn;
            unsigned int bits = (__builtin_bit_cast(unsigned int, hn) & ~3u) |
                                ((unsigned)(t + 1) & 3u);
            __hip_atomic_store(out_w + J0 + tid, bits, __ATOMIC_RELAXED,
                               __HIP_MEMORY_SCOPE_AGENT);
            outbase[((size_t)t << 9) + tid] = hn;
        }
        wcur = wnext;
        // no 3rd barrier: hsh re-staging for t+1 is gated by the t+1 poll,
        // which cannot pass until this block's producers store stamp t+1
        // (after their gsum reads post-barrier#2).
    }
}

// ---------------------------------------------------------------------------
// k_out: grouped output linear via MFMA 16x16x32 bf16, in-place on d_out
// (R12-proven).
// ---------------------------------------------------------------------------
__global__ __launch_bounds__(256) void k_out(const float* __restrict__ w_out, // [g][i][o]
                                             float* __restrict__ io) {
    __shared__ alignas(16) unsigned short At[32 * ALD];

    const int tid  = threadIdx.x;
    const int w    = tid >> 6;
    const int l    = tid & 63;
    const int kgrp = l >> 4;
    const int lc   = l & 15;
    const int row0 = blockIdx.x * 32;

    // ---- stage 32 rows x 512 f32 -> bf16 padded LDS ----
    for (int sidx = tid; sidx < 2048; sidx += 256) {
        int r = sidx >> 6, c8 = sidx & 63;
        const float4* src = (const float4*)(io + (size_t)(row0 + r) * 512 + c8 * 8);
        float4 v0 = src[0], v1 = src[1];
        unsigned short tmp[8] = {f2bf(v0.x), f2bf(v0.y), f2bf(v0.z), f2bf(v0.w),
                                 f2bf(v1.x), f2bf(v1.y), f2bf(v1.z), f2bf(v1.w)};
        *(bf16x8*)(At + r * ALD + c8 * 8) = *(bf16x8*)tmp;
    }
    __syncthreads();

    // ---- B fragments for this wave's 2 groups (16 frags, from L2) ----
    bf16x8 bfr[16];
#pragma unroll
    for (int gi = 0; gi < 2; ++gi) {
        const int g = 2 * w + gi;
#pragma unroll
        for (int kt = 0; kt < 2; ++kt) {
            const float* bsrc = w_out + (g << 12) + (kt * 32 + kgrp * 8) * 64 + lc;
#pragma unroll
            for (int nt = 0; nt < 4; ++nt) {
                unsigned short bw[8];
#pragma unroll
                for (int j = 0; j < 8; ++j) bw[j] = f2bf(bsrc[j * 64 + nt * 16]);
                bfr[(gi * 2 + kt) * 4 + nt] = *(bf16x8*)bw;
            }
        }
    }

    // ---- MFMA: 32 per wave ----
    f32x4 acc[2][8];
#pragma unroll
    for (int fr = 0; fr < 2; ++fr)
#pragma unroll
        for (int n = 0; n < 8; ++n) acc[fr][n] = f32x4{0.f, 0.f, 0.f, 0.f};

#pragma unroll
    for (int gi = 0; gi < 2; ++gi) {
        const int g = 2 * w + gi;
#pragma unroll
        for (int kt = 0; kt < 2; ++kt) {
            bf16x8 a0 = *(const bf16x8*)(At + lc        * ALD + g * 64 + kt * 32 + kgrp * 8);
            bf16x8 a1 = *(const bf16x8*)(At + (16 + lc) * ALD + g * 64 + kt * 32 + kgrp * 8);
#pragma unroll
            for (int nt = 0; nt < 4; ++nt) {
                bf16x8 bf = bfr[(gi * 2 + kt) * 4 + nt];
                acc[0][gi * 4 + nt] = __builtin_amdgcn_mfma_f32_16x16x32_bf16(a0, bf, acc[0][gi * 4 + nt], 0, 0, 0);
                acc[1][gi * 4 + nt] = __builtin_amdgcn_mfma_f32_16x16x32_bf16(a1, bf, acc[1][gi * 4 + nt], 0, 0, 0);
            }
        }
    }

    // ---- store (in-place; reads all done pre-barrier) ----
#pragma unroll
    for (int gi = 0; gi < 2; ++gi)
#pragma unroll
        for (int nt = 0; nt < 4; ++nt) {
            const int col = (2 * w + gi) * 64 + nt * 16 + lc;
#pragma unroll
            for (int fr = 0; fr < 2; ++fr)
#pragma unroll
                for (int r = 0; r < 4; ++r)
                    io[(size_t)(row0 + fr * 16 + kgrp * 4 + r) * 512 + col] =
                        acc[fr][gi * 4 + nt][r];
        }
}

// ---------------------------------------------------------------------------
extern "C" void kernel_launch(void* const* d_in, const int* in_sizes, int n_in,
                              void* d_out, int out_size, void* d_ws, size_t ws_size,
                              hipStream_t stream) {
    const float* x      = (const float*)d_in[0];
    const float* w_in   = (const float*)d_in[1];
    const float* w_rec  = (const float*)d_in[2];
    const float* u_rec  = (const float*)d_in[3];
    const float* gamma  = (const float*)d_in[4];
    const float* beta   = (const float*)d_in[5];
    const float* w_out  = (const float*)d_in[6];
    float* out = (float*)d_out;

    // workspace layout (131,203,072 B — proven bound)
    float*        w_pre = (float*)d_ws;                       // 32,768,000 f32
    unsigned int* hbuf  = (unsigned int*)(w_pre + (size_t)32 * T_LEN * 1024); // [2][32][512]

    // d_out staging (dead until k_scan overwrites it)
    unsigned short* hin = (unsigned short*)d_out;
    unsigned short* wrt = hin + (size_t)32000 * 512;

    hipLaunchKernelGGL(k1, dim3(1000), dim3(256), 0, stream,
                       x, w_in, w_rec, hin, wrt, hbuf);
    hipLaunchKernelGGL(k2, dim3(1000), dim3(256), 0, stream,
                       hin, wrt, gamma, beta, w_pre);
    hipLaunchKernelGGL(k_scan, dim3(256), dim3(1024), 0, stream,
                       w_pre, u_rec, out, hbuf);
    hipLaunchKernelGGL(k_out, dim3(1000), dim3(256), 0, stream, w_out, out);
}